// Round 1
// baseline (1545.739 us; speedup 1.0000x reference)
//
#include <hip/hip_runtime.h>
#include <math.h>

// Sinkhorn-divergence margin loss, MI355X.
// Scaled domain: F = f/(eps*ln2), M = C/(eps*ln2); softmin via exp2/log2.
#define NB 256
#define NL 256
#define ND 300
#define NC 5
#define NR 50

constexpr float SCf  = 577.07801635558534f;     // 1/(eps*ln2), eps=0.0025
constexpr float ELNf = 0.0017328679513998632f;  // eps*ln2
constexpr float BL2f = -5.6438561897747247f;    // log2(1/50)
constexpr float NEGB = -1.0e9f;

// workspace layout (floats)
#define WS_XN   0        // 65536
#define WS_AL2  65536    // 65536
#define WS_YN   131072   // 256
#define WS_PA   131328   // 256
#define WS_QC   131584   // 16
#define WS_S    131600   // 1280

__device__ __forceinline__ float ex2(float x){ return __builtin_amdgcn_exp2f(x); }
__device__ __forceinline__ float lg2(float x){ return __builtin_amdgcn_logf(x); } // v_log_f32 = log2

// ---------------- k_pre: norms (scaled) + log2-weights ----------------
__global__ __launch_bounds__(256) void k_pre(const float* __restrict__ anchor,
                                             const float* __restrict__ weight,
                                             const float* __restrict__ t0,
                                             float* __restrict__ ws){
  const int blk=blockIdx.x, t=threadIdx.x;
  if(blk<256){
    const int r=blk*256+t;
    const float4* row=(const float4*)(anchor+(size_t)r*ND);
    float s=0.f;
    #pragma unroll
    for(int k=0;k<75;k++){ float4 v=row[k];
      s=fmaf(v.x,v.x,fmaf(v.y,v.y,fmaf(v.z,v.z,fmaf(v.w,v.w,s)))); }
    ws[WS_XN+r]=0.5f*SCf*s;
    const float w=weight[r];
    ws[WS_AL2+r]=(w>0.f)?log2f(w):NEGB;
  } else if(t<NC*NR){
    const float4* row=(const float4*)(t0+(size_t)t*ND);
    float s=0.f;
    #pragma unroll
    for(int k=0;k<75;k++){ float4 v=row[k];
      s=fmaf(v.x,v.x,fmaf(v.y,v.y,fmaf(v.z,v.z,fmaf(v.w,v.w,s)))); }
    ws[WS_YN+t]=0.5f*SCf*s;
  }
}

// ---------------- k_ab: blocks 0..255 -> p-iteration per b; 256..260 -> q per c ----
__global__ __launch_bounds__(512) void k_ab(const float* __restrict__ anchor,
                                            const float* __restrict__ weight,
                                            const float* __restrict__ t0,
                                            float* __restrict__ ws){
  __shared__ __align__(16) float xt[256*20];
  __shared__ __align__(16) float xnL[256];
  __shared__ __align__(16) float Al2L[256];
  __shared__ __align__(16) float HpL[256];
  __shared__ float red[8];
  __shared__ float MyL[50*52];
  __shared__ float QL[64];
  const int blk=blockIdx.x, t=threadIdx.x;
  if(blk<256){
    const int b=blk, i=t>>1, h=t&1;
    const float* xb=anchor+(size_t)b*NL*ND;
    if(t<256){ xnL[t]=ws[WS_XN+b*256+t]; } else { Al2L[t-256]=ws[WS_AL2+b*256+(t-256)]; }
    float Mr[128];
    #pragma unroll
    for(int j=0;j<128;j++) Mr[j]=0.f;
    #pragma unroll 1
    for(int tile=0;tile<15;tile++){
      __syncthreads();
      { // stage x[256][20] for this d-tile
        const int r=t&255, p=t>>8;
        const float4* src=(const float4*)(xb+(size_t)r*ND+tile*20);
        if(p==0){ float4 v0=src[0],v1=src[1],v2=src[2];
          *(float4*)&xt[r*20+0]=v0; *(float4*)&xt[r*20+4]=v1; *(float4*)&xt[r*20+8]=v2;
        }else{ float4 v3=src[3],v4=src[4];
          *(float4*)&xt[r*20+12]=v3; *(float4*)&xt[r*20+16]=v4; }
      }
      __syncthreads();
      const float4* xrow=(const float4*)(xb+(size_t)i*ND+tile*20);
      #pragma unroll
      for(int d4=0;d4<5;d4++){
        const float4 xq=xrow[d4];
        #pragma unroll
        for(int jj=0;jj<128;jj++){
          const float4 yv=*(const float4*)&xt[(h*128+jj)*20+d4*4];
          Mr[jj]=fmaf(xq.x,yv.x,fmaf(xq.y,yv.y,fmaf(xq.z,yv.z,fmaf(xq.w,yv.w,Mr[jj]))));
        }
      }
    }
    __syncthreads();
    {
      const float xni=xnL[i];
      #pragma unroll
      for(int jj=0;jj<128;jj++) Mr[jj]=xni+xnL[h*128+jj]-SCf*Mr[jj];
    }
    if(h==0) HpL[i]=Al2L[i];   // P=0 initial state
    __syncthreads();
    float Pi=0.f;
    #pragma unroll 1
    for(int it=0; it<51; ++it){  // pass 0 = init softmin, then 50 averaged updates
      float m0=-3.0e38f,m1=-3.0e38f,m2=-3.0e38f,m3=-3.0e38f;
      #pragma unroll
      for(int q=0;q<32;q++){
        const float4 hv=*(const float4*)&HpL[h*128+q*4];
        m0=fmaxf(m0,hv.x-Mr[q*4+0]); m1=fmaxf(m1,hv.y-Mr[q*4+1]);
        m2=fmaxf(m2,hv.z-Mr[q*4+2]); m3=fmaxf(m3,hv.w-Mr[q*4+3]);
      }
      float m=fmaxf(fmaxf(m0,m1),fmaxf(m2,m3));
      m=fmaxf(m,__shfl_xor(m,1));
      float s0=0.f,s1=0.f,s2=0.f,s3=0.f;
      #pragma unroll
      for(int q=0;q<32;q++){
        const float4 hv=*(const float4*)&HpL[h*128+q*4];
        s0+=ex2(hv.x-Mr[q*4+0]-m); s1+=ex2(hv.y-Mr[q*4+1]-m);
        s2+=ex2(hv.z-Mr[q*4+2]-m); s3+=ex2(hv.w-Mr[q*4+3]-m);
      }
      float s=(s0+s1)+(s2+s3);
      s+=__shfl_xor(s,1);
      const float sm=-(m+lg2(s));
      Pi=(it==0)?sm:0.5f*(Pi+sm);
      __syncthreads();
      if(h==0) HpL[i]=Al2L[i]+Pi;
      __syncthreads();
    }
    float cv=(h==0)?(weight[b*256+i]*Pi):0.f;
    #pragma unroll
    for(int off=1;off<64;off<<=1) cv+=__shfl_xor(cv,off);
    if((t&63)==0) red[t>>6]=cv;
    __syncthreads();
    if(t==0){ float ss=0.f;
      #pragma unroll
      for(int k=0;k<8;k++) ss+=red[k];
      ws[WS_PA+b]=ELNf*ss; }
  } else {
    const int c=blk-256;
    const float* yc=t0+(size_t)c*NR*ND;
    #pragma unroll 1
    for(int rr=0;rr<5;rr++){
      const int o=t+512*rr;
      if(o<2500){
        const int j=o/50, k=o-j*50;
        const float4* a4=(const float4*)(yc+(size_t)j*ND);
        const float4* b4=(const float4*)(yc+(size_t)k*ND);
        float s=0.f;
        #pragma unroll
        for(int d4=0;d4<75;d4++){ const float4 av=a4[d4],bv=b4[d4];
          s=fmaf(av.x,bv.x,fmaf(av.y,bv.y,fmaf(av.z,bv.z,fmaf(av.w,bv.w,s)))); }
        MyL[j*52+k]=ws[WS_YN+c*50+j]+ws[WS_YN+c*50+k]-SCf*s;
      }
    }
    if(t<64) QL[t]=0.f;
    __syncthreads();
    float My[50]; float Qj=0.f;
    if(t<50){
      #pragma unroll
      for(int k=0;k<50;k++) My[k]=MyL[t*52+k];
    }
    #pragma unroll 1
    for(int it=0; it<51; ++it){
      float sm=0.f;
      if(t<50){
        float m=-3.0e38f; float sc[50];
        #pragma unroll
        for(int k=0;k<50;k++){ sc[k]=BL2f+QL[k]-My[k]; m=fmaxf(m,sc[k]); }
        float s=0.f;
        #pragma unroll
        for(int k=0;k<50;k++) s+=ex2(sc[k]-m);
        sm=-(m+lg2(s));
      }
      __syncthreads();
      if(t<50){ Qj=(it==0)?sm:0.5f*(Qj+sm); QL[t]=Qj; }
      __syncthreads();
    }
    float cv=(t<50)?Qj:0.f;
    if(t<64){
      #pragma unroll
      for(int off=1;off<64;off<<=1) cv+=__shfl_xor(cv,off);
    }
    if(t==0) ws[WS_QC+c]=ELNf*0.02f*cv;
  }
}

// ---------------- k_c: f,g iteration per (b,c) ----------------
__global__ __launch_bounds__(256) void k_c(const float* __restrict__ anchor,
                                           const float* __restrict__ weight,
                                           const float* __restrict__ t0,
                                           float* __restrict__ ws){
  __shared__ __align__(16) float MTL[50*260]; // phase0: y-stage [50][20]; then M^T [50][4*65]
  __shared__ __align__(16) float Al2L[256];
  __shared__ __align__(16) float AfL[256];
  __shared__ __align__(16) float GL[64];
  __shared__ float red[4];
  const int blk=blockIdx.x, t=threadIdx.x;
  const int c=blk>>8, b=blk&255;
  const float* xb=anchor+(size_t)b*NL*ND;
  const float* yc=t0+(size_t)c*NR*ND;
  Al2L[t]=ws[WS_AL2+b*256+t];
  if(t<64) GL[t]=0.f;
  float Mr[50];
  #pragma unroll
  for(int j=0;j<50;j++) Mr[j]=0.f;
  #pragma unroll 1
  for(int tile=0;tile<15;tile++){
    __syncthreads();
    if(t<250){
      const int j=t/5, dd=(t-j*5)*4;
      const float4 v=*(const float4*)(yc+(size_t)j*ND+tile*20+dd);
      *(float4*)&MTL[j*20+dd]=v;
    }
    __syncthreads();
    const float4* xrow=(const float4*)(xb+(size_t)t*ND+tile*20);
    #pragma unroll
    for(int d4=0;d4<5;d4++){
      const float4 xq=xrow[d4];
      #pragma unroll
      for(int j=0;j<50;j++){
        const float4 yv=*(const float4*)&MTL[j*20+d4*4];
        Mr[j]=fmaf(xq.x,yv.x,fmaf(xq.y,yv.y,fmaf(xq.z,yv.z,fmaf(xq.w,yv.w,Mr[j]))));
      }
    }
  }
  __syncthreads();
  {
    const float xni=ws[WS_XN+b*256+t];
    #pragma unroll
    for(int j=0;j<50;j++) Mr[j]=xni+ws[WS_YN+c*50+j]-SCf*Mr[j];
  }
  { // transpose into LDS: MT[j][q*65+r], bank = (4j+q+r)%32 = (t_reader + r)%32 -> conflict-free
    const int q=t>>6, r=t&63;
    #pragma unroll
    for(int j=0;j<50;j++) MTL[j*260+q*65+r]=Mr[j];
  }
  AfL[t]=Al2L[t];  // F=0 initial state
  __syncthreads();
  float Fi=0.f, Gj=0.f;
  const int gj=t>>2, gq=t&3;
  #pragma unroll 1
  for(int it=0; it<51; ++it){
    float scr[64];
    // f-pass: row t over 50 cols (M in regs, G broadcast from LDS)
    float f0=-3.0e38f,f1=-3.0e38f,f2=-3.0e38f,f3=-3.0e38f;
    #pragma unroll
    for(int j4=0;j4<12;j4++){
      const float4 gv=*(const float4*)&GL[j4*4];
      scr[j4*4+0]=BL2f+gv.x-Mr[j4*4+0]; scr[j4*4+1]=BL2f+gv.y-Mr[j4*4+1];
      scr[j4*4+2]=BL2f+gv.z-Mr[j4*4+2]; scr[j4*4+3]=BL2f+gv.w-Mr[j4*4+3];
      f0=fmaxf(f0,scr[j4*4+0]); f1=fmaxf(f1,scr[j4*4+1]);
      f2=fmaxf(f2,scr[j4*4+2]); f3=fmaxf(f3,scr[j4*4+3]);
    }
    scr[48]=BL2f+GL[48]-Mr[48]; scr[49]=BL2f+GL[49]-Mr[49];
    f0=fmaxf(f0,scr[48]); f1=fmaxf(f1,scr[49]);
    const float fm=fmaxf(fmaxf(f0,f1),fmaxf(f2,f3));
    float fs0=0.f,fs1=0.f,fs2=0.f,fs3=0.f;
    #pragma unroll
    for(int j4=0;j4<12;j4++){
      fs0+=ex2(scr[j4*4+0]-fm); fs1+=ex2(scr[j4*4+1]-fm);
      fs2+=ex2(scr[j4*4+2]-fm); fs3+=ex2(scr[j4*4+3]-fm);
    }
    fs0+=ex2(scr[48]-fm); fs1+=ex2(scr[49]-fm);
    const float smf=-(fm+lg2((fs0+fs1)+(fs2+fs3)));
    // g-pass: col gj, rows gq*64..+63 (M^T from LDS, Af broadcast)
    float smg=0.f;
    if(t<200){
      float g0=-3.0e38f,g1=-3.0e38f,g2=-3.0e38f,g3=-3.0e38f;
      #pragma unroll
      for(int r4=0;r4<16;r4++){
        const float4 av=*(const float4*)&AfL[gq*64+r4*4];
        const int base=gj*260+gq*65+r4*4;
        const float u0=av.x-MTL[base+0]; const float u1=av.y-MTL[base+1];
        const float u2=av.z-MTL[base+2]; const float u3=av.w-MTL[base+3];
        scr[r4*4+0]=u0; scr[r4*4+1]=u1; scr[r4*4+2]=u2; scr[r4*4+3]=u3;
        g0=fmaxf(g0,u0); g1=fmaxf(g1,u1); g2=fmaxf(g2,u2); g3=fmaxf(g3,u3);
      }
      float gm=fmaxf(fmaxf(g0,g1),fmaxf(g2,g3));
      gm=fmaxf(gm,__shfl_xor(gm,1));
      gm=fmaxf(gm,__shfl_xor(gm,2));
      float gs0=0.f,gs1=0.f,gs2=0.f,gs3=0.f;
      #pragma unroll
      for(int r4=0;r4<16;r4++){
        gs0+=ex2(scr[r4*4+0]-gm); gs1+=ex2(scr[r4*4+1]-gm);
        gs2+=ex2(scr[r4*4+2]-gm); gs3+=ex2(scr[r4*4+3]-gm);
      }
      float gs=(gs0+gs1)+(gs2+gs3);
      gs+=__shfl_xor(gs,1);
      gs+=__shfl_xor(gs,2);
      smg=-(gm+lg2(gs));
    }
    Fi=(it==0)?smf:0.5f*(Fi+smf);
    if(t<200) Gj=(it==0)?smg:0.5f*(Gj+smg);
    __syncthreads();
    AfL[t]=Al2L[t]+Fi;
    if(t<200 && gq==0) GL[gj]=Gj;
    __syncthreads();
  }
  // S[b,c] = ELN*(sum_i a_i F_i + 0.02*sum_j G_j)
  float cv=weight[b*256+t]*Fi;
  #pragma unroll
  for(int off=1;off<64;off<<=1) cv+=__shfl_xor(cv,off);
  if((t&63)==0) red[t>>6]=cv;
  __syncthreads();
  if(t==0){
    float sa=red[0]+red[1]+red[2]+red[3];
    float sg=0.f;
    #pragma unroll
    for(int j=0;j<50;j++) sg+=GL[j];
    ws[WS_S+b*NC+c]=ELNf*(sa+0.02f*sg);
  }
}

// ---------------- k_d: margin loss + mean ----------------
__global__ __launch_bounds__(256) void k_d(const int* __restrict__ grade,
                                           const float* __restrict__ ws,
                                           float* __restrict__ out){
  __shared__ float red[4];
  const int t=threadIdx.x;
  const int g=grade[t];
  const float pa=ws[WS_PA+t];
  const float d0=ws[WS_S+t*NC+0]-pa-ws[WS_QC+0];
  const float d1=ws[WS_S+t*NC+1]-pa-ws[WS_QC+1];
  const float d2=ws[WS_S+t*NC+2]-pa-ws[WS_QC+2];
  const float d3=ws[WS_S+t*NC+3]-pa-ws[WS_QC+3];
  const float d4=ws[WS_S+t*NC+4]-pa-ws[WS_QC+4];
  const float pos=(g==0)?d0:(g==1)?d1:(g==2)?d2:(g==3)?d3:d4;
  float loss=0.f;
  if(g!=0) loss+=fmaxf(0.f,pos-d0+10.f);
  if(g!=1) loss+=fmaxf(0.f,pos-d1+10.f);
  if(g!=2) loss+=fmaxf(0.f,pos-d2+10.f);
  if(g!=3) loss+=fmaxf(0.f,pos-d3+10.f);
  if(g!=4) loss+=fmaxf(0.f,pos-d4+10.f);
  loss*=0.2f;
  #pragma unroll
  for(int off=1;off<64;off<<=1) loss+=__shfl_xor(loss,off);
  if((t&63)==0) red[t>>6]=loss;
  __syncthreads();
  if(t==0) out[0]=(red[0]+red[1]+red[2]+red[3])*(1.f/256.f);
}

extern "C" void kernel_launch(void* const* d_in, const int* in_sizes, int n_in,
                              void* d_out, int out_size, void* d_ws, size_t ws_size,
                              hipStream_t stream){
  (void)in_sizes;(void)n_in;(void)out_size;(void)ws_size;
  const float* anchor=(const float*)d_in[0];
  const float* weight=(const float*)d_in[1];
  const float* t0    =(const float*)d_in[2];
  const int*   grade =(const int*)d_in[5];
  float* ws=(float*)d_ws;
  float* out=(float*)d_out;
  k_pre<<<257,256,0,stream>>>(anchor,weight,t0,ws);
  k_ab <<<261,512,0,stream>>>(anchor,weight,t0,ws);
  k_c  <<<1280,256,0,stream>>>(anchor,weight,t0,ws);
  k_d  <<<1,256,0,stream>>>(grade,ws,out);
}

// Round 2
// 970.461 us; speedup vs baseline: 1.5928x; 1.5928x over previous
//
#include <hip/hip_runtime.h>
#include <math.h>

// Sinkhorn-divergence margin loss, MI355X.
// Scaled domain: F = f/(eps*ln2), M = C/(eps*ln2); softmin via exp2/log2.
#define NB 256
#define NL 256
#define ND 300
#define NC 5
#define NR 50

constexpr float SCf  = 577.07801635558534f;     // 1/(eps*ln2), eps=0.0025
constexpr float ELNf = 0.0017328679513998632f;  // eps*ln2
constexpr float BL2f = -5.6438561897747247f;    // log2(1/50)
constexpr float NEGB = -1.0e9f;

// workspace layout (floats)
#define WS_XN   0        // 65536
#define WS_AL2  65536    // 65536
#define WS_YN   131072   // 256
#define WS_PA   131328   // 256
#define WS_QC   131584   // 16
#define WS_S    131600   // 1280

__device__ __forceinline__ float ex2(float x){ return __builtin_amdgcn_exp2f(x); }
__device__ __forceinline__ float lg2(float x){ return __builtin_amdgcn_logf(x); } // v_log_f32 = log2

// ---------------- k_pre: norms (scaled) + log2-weights ----------------
__global__ __launch_bounds__(256) void k_pre(const float* __restrict__ anchor,
                                             const float* __restrict__ weight,
                                             const float* __restrict__ t0,
                                             float* __restrict__ ws){
  const int blk=blockIdx.x, t=threadIdx.x;
  if(blk<256){
    const int r=blk*256+t;
    const float4* row=(const float4*)(anchor+(size_t)r*ND);
    float s=0.f;
    #pragma unroll
    for(int k=0;k<75;k++){ float4 v=row[k];
      s=fmaf(v.x,v.x,fmaf(v.y,v.y,fmaf(v.z,v.z,fmaf(v.w,v.w,s)))); }
    ws[WS_XN+r]=0.5f*SCf*s;
    const float w=weight[r];
    ws[WS_AL2+r]=(w>0.f)?log2f(w):NEGB;
  } else if(t<NC*NR){
    const float4* row=(const float4*)(t0+(size_t)t*ND);
    float s=0.f;
    #pragma unroll
    for(int k=0;k<75;k++){ float4 v=row[k];
      s=fmaf(v.x,v.x,fmaf(v.y,v.y,fmaf(v.z,v.z,fmaf(v.w,v.w,s)))); }
    ws[WS_YN+t]=0.5f*SCf*s;
  }
}

// ---------------- k_ab: blocks 0..255 -> p per b (1024 thr, 4 thr/row); 256..260 -> q per c ----
__global__ __launch_bounds__(1024) void k_ab(const float* __restrict__ anchor,
                                             const float* __restrict__ weight,
                                             const float* __restrict__ t0,
                                             float* __restrict__ ws){
  __shared__ __align__(16) float4 xt4[1288];  // swizzled x-tile: xt4[5r + 2*(r>>6) + d4]
  __shared__ __align__(16) float xnL[256];
  __shared__ __align__(16) float HpP[4*68];   // H padded: [q*68 + r], col j -> (j>>6)*68+(j&63)
  __shared__ float red[16];
  __shared__ __align__(16) float MyL[50*52];
  __shared__ float QL[64];
  const int blk=blockIdx.x, t=threadIdx.x;
  if(blk<256){
    const int b=blk, i=t>>2, h=t&3;
    const float* xb=anchor+(size_t)b*NL*ND;
    if(t<256) xnL[t]=ws[WS_XN+b*256+t];
    const float al2=ws[WS_AL2+b*256+i];
    float Mr[64];
    #pragma unroll
    for(int j=0;j<64;j++) Mr[j]=0.f;
    #pragma unroll 1
    for(int tile=0;tile<15;tile++){
      __syncthreads();
      { // stage x[256][20], swizzled by +2 float4 per 64-row block
        int e=t;
        if(e<1280){ const int r=e/5, d4=e-r*5;
          xt4[5*r+2*(r>>6)+d4]=*(const float4*)(xb+(size_t)r*ND+tile*20+d4*4); }
        e=t+1024;
        if(e<1280){ const int r=e/5, d4=e-r*5;
          xt4[5*r+2*(r>>6)+d4]=*(const float4*)(xb+(size_t)r*ND+tile*20+d4*4); }
      }
      __syncthreads();
      const float4* xrow=(const float4*)(xb+(size_t)i*ND+tile*20);
      const float4 xq0=xrow[0],xq1=xrow[1],xq2=xrow[2],xq3=xrow[3],xq4=xrow[4];
      const int cb=322*h;  // 5*(64h) + 2h
      #pragma unroll
      for(int jj=0;jj<64;jj++){
        const float4 y0=xt4[cb+5*jj+0];
        const float4 y1=xt4[cb+5*jj+1];
        const float4 y2=xt4[cb+5*jj+2];
        const float4 y3=xt4[cb+5*jj+3];
        const float4 y4=xt4[cb+5*jj+4];
        float acc=Mr[jj];
        acc=fmaf(xq0.x,y0.x,fmaf(xq0.y,y0.y,fmaf(xq0.z,y0.z,fmaf(xq0.w,y0.w,acc))));
        acc=fmaf(xq1.x,y1.x,fmaf(xq1.y,y1.y,fmaf(xq1.z,y1.z,fmaf(xq1.w,y1.w,acc))));
        acc=fmaf(xq2.x,y2.x,fmaf(xq2.y,y2.y,fmaf(xq2.z,y2.z,fmaf(xq2.w,y2.w,acc))));
        acc=fmaf(xq3.x,y3.x,fmaf(xq3.y,y3.y,fmaf(xq3.z,y3.z,fmaf(xq3.w,y3.w,acc))));
        acc=fmaf(xq4.x,y4.x,fmaf(xq4.y,y4.y,fmaf(xq4.z,y4.z,fmaf(xq4.w,y4.w,acc))));
        Mr[jj]=acc;
      }
    }
    __syncthreads();
    {
      const float xni=xnL[i];
      #pragma unroll
      for(int jj=0;jj<64;jj++) Mr[jj]=xni+xnL[h*64+jj]-SCf*Mr[jj];
    }
    if(h==0) HpP[(i>>6)*68+(i&63)]=al2;  // P=0 init
    __syncthreads();
    float Pi=0.f;
    const float4* Hp4=(const float4*)HpP;
    #pragma unroll 1
    for(int it=0; it<51; ++it){
      float m0=-3.0e38f,m1=-3.0e38f,m2=-3.0e38f,m3=-3.0e38f;
      #pragma unroll
      for(int q=0;q<16;q++){
        const float4 hv=Hp4[h*17+q];
        m0=fmaxf(m0,hv.x-Mr[q*4+0]); m1=fmaxf(m1,hv.y-Mr[q*4+1]);
        m2=fmaxf(m2,hv.z-Mr[q*4+2]); m3=fmaxf(m3,hv.w-Mr[q*4+3]);
      }
      float m=fmaxf(fmaxf(m0,m1),fmaxf(m2,m3));
      m=fmaxf(m,__shfl_xor(m,1));
      m=fmaxf(m,__shfl_xor(m,2));
      float s0=0.f,s1=0.f,s2=0.f,s3=0.f;
      #pragma unroll
      for(int q=0;q<16;q++){
        const float4 hv=Hp4[h*17+q];
        s0+=ex2(hv.x-Mr[q*4+0]-m); s1+=ex2(hv.y-Mr[q*4+1]-m);
        s2+=ex2(hv.z-Mr[q*4+2]-m); s3+=ex2(hv.w-Mr[q*4+3]-m);
      }
      float s=(s0+s1)+(s2+s3);
      s+=__shfl_xor(s,1);
      s+=__shfl_xor(s,2);
      const float sm=-(m+lg2(s));
      Pi=(it==0)?sm:0.5f*(Pi+sm);
      __syncthreads();
      if(h==0) HpP[(i>>6)*68+(i&63)]=al2+Pi;
      __syncthreads();
    }
    float cv=(h==0)?(weight[b*256+i]*Pi):0.f;
    #pragma unroll
    for(int off=1;off<64;off<<=1) cv+=__shfl_xor(cv,off);
    if((t&63)==0) red[t>>6]=cv;
    __syncthreads();
    if(t==0){ float ss=0.f;
      #pragma unroll
      for(int k=0;k<16;k++) ss+=red[k];
      ws[WS_PA+b]=ELNf*ss; }
  } else {
    const int c=blk-256;
    const float* yc=t0+(size_t)c*NR*ND;
    #pragma unroll 1
    for(int rr=0;rr<3;rr++){
      const int o=t+1024*rr;
      if(o<2500){
        const int j=o/50, k=o-j*50;
        const float4* a4=(const float4*)(yc+(size_t)j*ND);
        const float4* b4=(const float4*)(yc+(size_t)k*ND);
        float s=0.f;
        #pragma unroll
        for(int d4=0;d4<75;d4++){ const float4 av=a4[d4],bv=b4[d4];
          s=fmaf(av.x,bv.x,fmaf(av.y,bv.y,fmaf(av.z,bv.z,fmaf(av.w,bv.w,s)))); }
        MyL[j*52+k]=ws[WS_YN+c*50+j]+ws[WS_YN+c*50+k]-SCf*s;
      }
    }
    if(t<64) QL[t]=0.f;
    __syncthreads();
    float My[50]; float Qj=0.f;
    if(t<50){
      #pragma unroll
      for(int k=0;k<50;k++) My[k]=MyL[t*52+k];
    }
    #pragma unroll 1
    for(int it=0; it<51; ++it){
      float sm=0.f;
      if(t<50){
        float m=-3.0e38f; float sc[50];
        #pragma unroll
        for(int k=0;k<50;k++){ sc[k]=BL2f+QL[k]-My[k]; m=fmaxf(m,sc[k]); }
        float s=0.f;
        #pragma unroll
        for(int k=0;k<50;k++) s+=ex2(sc[k]-m);
        sm=-(m+lg2(s));
      }
      __syncthreads();
      if(t<50){ Qj=(it==0)?sm:0.5f*(Qj+sm); QL[t]=Qj; }
      __syncthreads();
    }
    float cv=(t<64)?((t<50)?Qj:0.f):0.f;
    if(t<64){
      #pragma unroll
      for(int off=1;off<64;off<<=1) cv+=__shfl_xor(cv,off);
    }
    if(t==0) ws[WS_QC+c]=ELNf*0.02f*cv;
  }
}

// ---------------- k_c: f,g iteration per (b,c); 512 thr, 2 thr/row, 8 thr/col ----------------
__global__ __launch_bounds__(512,4) void k_c(const float* __restrict__ anchor,
                                             const float* __restrict__ weight,
                                             const float* __restrict__ t0,
                                             float* __restrict__ ws){
  __shared__ __align__(16) float4 MT4[50*66]; // M^T swizzled: MT4[j*66 + ((i>>2)^(j&7))], comp i&3
  __shared__ __align__(16) float yt[1000];    // y-tile [50][20]
  __shared__ float ynL[50];
  __shared__ __align__(16) float AfP[8*36];   // Al2+F padded: [ (i>>5)*36 + (i&31) ]
  __shared__ float GL[52];
  __shared__ float red[8];
  const int blk=blockIdx.x, t=threadIdx.x;
  const int c=blk>>8, b=blk&255;
  const int i=t>>1, h=t&1;
  const float* xb=anchor+(size_t)b*NL*ND;
  const float* yc=t0+(size_t)c*NR*ND;
  if(t<50){ ynL[t]=ws[WS_YN+c*50+t]; GL[t]=0.f; }
  const float al2=ws[WS_AL2+b*256+i];
  const float xni=ws[WS_XN+b*256+i];
  float Mr[25];
  #pragma unroll
  for(int k=0;k<25;k++) Mr[k]=0.f;
  #pragma unroll 1
  for(int tile=0;tile<15;tile++){
    __syncthreads();
    if(t<250){
      const int j=t/5, d4=t-j*5;
      *(float4*)&yt[j*20+d4*4]=*(const float4*)(yc+(size_t)j*ND+tile*20+d4*4);
    }
    __syncthreads();
    const float4* xrow=(const float4*)(xb+(size_t)i*ND+tile*20);
    const float4 xq0=xrow[0],xq1=xrow[1],xq2=xrow[2],xq3=xrow[3],xq4=xrow[4];
    #pragma unroll
    for(int k=0;k<25;k++){
      const int j=2*k+h;
      const float4 y0=*(const float4*)&yt[j*20+0];
      const float4 y1=*(const float4*)&yt[j*20+4];
      const float4 y2=*(const float4*)&yt[j*20+8];
      const float4 y3=*(const float4*)&yt[j*20+12];
      const float4 y4=*(const float4*)&yt[j*20+16];
      float acc=Mr[k];
      acc=fmaf(xq0.x,y0.x,fmaf(xq0.y,y0.y,fmaf(xq0.z,y0.z,fmaf(xq0.w,y0.w,acc))));
      acc=fmaf(xq1.x,y1.x,fmaf(xq1.y,y1.y,fmaf(xq1.z,y1.z,fmaf(xq1.w,y1.w,acc))));
      acc=fmaf(xq2.x,y2.x,fmaf(xq2.y,y2.y,fmaf(xq2.z,y2.z,fmaf(xq2.w,y2.w,acc))));
      acc=fmaf(xq3.x,y3.x,fmaf(xq3.y,y3.y,fmaf(xq3.z,y3.z,fmaf(xq3.w,y3.w,acc))));
      acc=fmaf(xq4.x,y4.x,fmaf(xq4.y,y4.y,fmaf(xq4.z,y4.z,fmaf(xq4.w,y4.w,acc))));
      Mr[k]=acc;
    }
  }
  __syncthreads();
  #pragma unroll
  for(int k=0;k<25;k++){
    const int j=2*k+h;
    Mr[k]=xni+ynL[j]-SCf*Mr[k];
  }
  { // transpose into swizzled MT4 (2-way write conflicts only)
    const int Q=i>>2, cc=i&3;
    #pragma unroll
    for(int k=0;k<25;k++){
      const int j=2*k+h;
      ((float*)&MT4[j*66+(Q^(j&7))])[cc]=Mr[k];
    }
  }
  if(h==0) AfP[(i>>5)*36+(i&31)]=al2;  // F=0 init
  __syncthreads();
  float Fi=0.f, Gj=0.f;
  const int gj=t>>3, gq=t&7, gx=gj&7;
  #pragma unroll 1
  for(int it=0; it<51; ++it){
    // ---- f-pass: row i over its 25 cols (M in regs, G broadcast) ----
    float scf[25];
    float mf=-3.0e38f;
    #pragma unroll
    for(int k=0;k<25;k++){
      scf[k]=BL2f+GL[2*k+h]-Mr[k];
      mf=fmaxf(mf,scf[k]);
    }
    mf=fmaxf(mf,__shfl_xor(mf,1));
    float f0=0.f,f1=0.f,f2=0.f,f3=0.f;
    #pragma unroll
    for(int k=0;k<24;k+=4){
      f0+=ex2(scf[k+0]-mf); f1+=ex2(scf[k+1]-mf);
      f2+=ex2(scf[k+2]-mf); f3+=ex2(scf[k+3]-mf);
    }
    f0+=ex2(scf[24]-mf);
    float fs=(f0+f1)+(f2+f3);
    fs+=__shfl_xor(fs,1);
    const float smf=-(mf+lg2(fs));
    // ---- g-pass: col gj, rows gq*32..+31 (M^T + AfP from LDS, conflict-free b128) ----
    float smg=0.f;
    if(t<400){
      float scg[32];
      float g0=-3.0e38f,g1=-3.0e38f,g2=-3.0e38f,g3=-3.0e38f;
      #pragma unroll
      for(int r4=0;r4<8;r4++){
        const float4 av=*(const float4*)&AfP[36*gq+4*r4];
        const float4 mv=MT4[gj*66+((gq*8+r4)^gx)];
        const float u0=av.x-mv.x, u1=av.y-mv.y, u2=av.z-mv.z, u3=av.w-mv.w;
        scg[4*r4+0]=u0; scg[4*r4+1]=u1; scg[4*r4+2]=u2; scg[4*r4+3]=u3;
        g0=fmaxf(g0,u0); g1=fmaxf(g1,u1); g2=fmaxf(g2,u2); g3=fmaxf(g3,u3);
      }
      float gm=fmaxf(fmaxf(g0,g1),fmaxf(g2,g3));
      gm=fmaxf(gm,__shfl_xor(gm,1));
      gm=fmaxf(gm,__shfl_xor(gm,2));
      gm=fmaxf(gm,__shfl_xor(gm,4));
      float s0=0.f,s1=0.f,s2=0.f,s3=0.f;
      #pragma unroll
      for(int r4=0;r4<8;r4++){
        s0+=ex2(scg[4*r4+0]-gm); s1+=ex2(scg[4*r4+1]-gm);
        s2+=ex2(scg[4*r4+2]-gm); s3+=ex2(scg[4*r4+3]-gm);
      }
      float gsum=(s0+s1)+(s2+s3);
      gsum+=__shfl_xor(gsum,1);
      gsum+=__shfl_xor(gsum,2);
      gsum+=__shfl_xor(gsum,4);
      smg=-(gm+lg2(gsum));
    }
    Fi=(it==0)?smf:0.5f*(Fi+smf);
    if(t<400) Gj=(it==0)?smg:0.5f*(Gj+smg);
    __syncthreads();
    if(h==0) AfP[(i>>5)*36+(i&31)]=al2+Fi;
    if(t<400 && gq==0) GL[gj]=Gj;
    __syncthreads();
  }
  // S[b,c] = ELN*(sum_i a_i F_i + 0.02*sum_j G_j)
  float cv=(h==0)?(weight[b*256+i]*Fi):0.f;
  #pragma unroll
  for(int off=1;off<64;off<<=1) cv+=__shfl_xor(cv,off);
  if((t&63)==0) red[t>>6]=cv;
  __syncthreads();
  if(t==0){
    float sa=0.f;
    #pragma unroll
    for(int k=0;k<8;k++) sa+=red[k];
    float sg=0.f;
    #pragma unroll
    for(int j=0;j<50;j++) sg+=GL[j];
    ws[WS_S+b*NC+c]=ELNf*(sa+0.02f*sg);
  }
}

// ---------------- k_d: margin loss + mean ----------------
__global__ __launch_bounds__(256) void k_d(const int* __restrict__ grade,
                                           const float* __restrict__ ws,
                                           float* __restrict__ out){
  __shared__ float red[4];
  const int t=threadIdx.x;
  const int g=grade[t];
  const float pa=ws[WS_PA+t];
  const float d0=ws[WS_S+t*NC+0]-pa-ws[WS_QC+0];
  const float d1=ws[WS_S+t*NC+1]-pa-ws[WS_QC+1];
  const float d2=ws[WS_S+t*NC+2]-pa-ws[WS_QC+2];
  const float d3=ws[WS_S+t*NC+3]-pa-ws[WS_QC+3];
  const float d4=ws[WS_S+t*NC+4]-pa-ws[WS_QC+4];
  const float pos=(g==0)?d0:(g==1)?d1:(g==2)?d2:(g==3)?d3:d4;
  float loss=0.f;
  if(g!=0) loss+=fmaxf(0.f,pos-d0+10.f);
  if(g!=1) loss+=fmaxf(0.f,pos-d1+10.f);
  if(g!=2) loss+=fmaxf(0.f,pos-d2+10.f);
  if(g!=3) loss+=fmaxf(0.f,pos-d3+10.f);
  if(g!=4) loss+=fmaxf(0.f,pos-d4+10.f);
  loss*=0.2f;
  #pragma unroll
  for(int off=1;off<64;off<<=1) loss+=__shfl_xor(loss,off);
  if((t&63)==0) red[t>>6]=loss;
  __syncthreads();
  if(t==0) out[0]=(red[0]+red[1]+red[2]+red[3])*(1.f/256.f);
}

extern "C" void kernel_launch(void* const* d_in, const int* in_sizes, int n_in,
                              void* d_out, int out_size, void* d_ws, size_t ws_size,
                              hipStream_t stream){
  (void)in_sizes;(void)n_in;(void)out_size;(void)ws_size;
  const float* anchor=(const float*)d_in[0];
  const float* weight=(const float*)d_in[1];
  const float* t0    =(const float*)d_in[2];
  const int*   grade =(const int*)d_in[5];
  float* ws=(float*)d_ws;
  float* out=(float*)d_out;
  k_pre<<<257,256,0,stream>>>(anchor,weight,t0,ws);
  k_ab <<<261,1024,0,stream>>>(anchor,weight,t0,ws);
  k_c  <<<1280,512,0,stream>>>(anchor,weight,t0,ws);
  k_d  <<<1,256,0,stream>>>(grade,ws,out);
}